// Round 5
// baseline (1866.514 us; speedup 1.0000x reference)
//
#include <hip/hip_runtime.h>
#include <cstdint>
#include <cstddef>

#define NN 250000   // nodes
#define FF 256      // channels
#define GG 4096     // graphs
#define TT 6        // processing steps
#define NBLK 512    // persistent blocks: 2/CU on 256 CUs

typedef _Float16 half8_t __attribute__((ext_vector_type(8)));
typedef _Float16 half4_t __attribute__((ext_vector_type(4)));
typedef float f32x4 __attribute__((ext_vector_type(4)));

// ---- 2-level grid barrier: 16 groups x 32 blocks ----
// bar layout (ints, 64B-padded): [gi*16] group counters (16 groups),
// [256] root counter, [272 + gi*16] per-group release flags (epoch).
__device__ __forceinline__ void grid_barrier(int* bar, int epoch, int bid) {
  __syncthreads();
  if (threadIdx.x == 0) {
    __threadfence();  // release all prior global writes (agent scope)
    int gi = bid >> 5;
    int* gcnt  = bar + gi * 16;
    int* root  = bar + 256;
    int* gflag = bar + 272 + gi * 16;
    if (__hip_atomic_fetch_add(gcnt, 1, __ATOMIC_ACQ_REL,
                               __HIP_MEMORY_SCOPE_AGENT) == 31) {
      __hip_atomic_store(gcnt, 0, __ATOMIC_RELAXED, __HIP_MEMORY_SCOPE_AGENT);
      if (__hip_atomic_fetch_add(root, 1, __ATOMIC_ACQ_REL,
                                 __HIP_MEMORY_SCOPE_AGENT) == 15) {
        __hip_atomic_store(root, 0, __ATOMIC_RELAXED, __HIP_MEMORY_SCOPE_AGENT);
        for (int k = 0; k < 16; ++k)
          __hip_atomic_store(bar + 272 + k * 16, epoch, __ATOMIC_RELEASE,
                             __HIP_MEMORY_SCOPE_AGENT);
      }
    }
    while (__hip_atomic_load(gflag, __ATOMIC_ACQUIRE,
                             __HIP_MEMORY_SCOPE_AGENT) < epoch)
      __builtin_amdgcn_s_sleep(8);
    __threadfence();  // acquire
  }
  __syncthreads();
}

// ---- single-pass online-softmax attention for one graph (R2-proven loop) ----
// XMODE 1: NT-load x32, write x16 mirror (t=0). XMODE 2: read x16.
template <int XMODE>
__device__ __forceinline__ void attn_graph(
    int g, int s0, int cnt, const float* __restrict__ x32,
    const _Float16* __restrict__ x16r, _Float16* __restrict__ x16w,
    const float* qrow, float* __restrict__ qstar, _Float16* __restrict__ q16out,
    float* rw, float* mw, float* sw) {
  int tid = threadIdx.x, lane = tid & 63, w = tid >> 6;
  f32x4 qv = *(const f32x4*)(qrow + 4 * lane);

  float m = -INFINITY, ssum = 0.f;
  f32x4 racc = {0.f, 0.f, 0.f, 0.f};
  for (int i = w; i < cnt; i += 4) {
    size_t base = (size_t)(s0 + i) * FF + 4 * lane;
    f32x4 xv;
    if (XMODE == 2) {
      half4_t hx = *(const half4_t*)(x16r + base);
      xv[0] = (float)hx[0]; xv[1] = (float)hx[1];
      xv[2] = (float)hx[2]; xv[3] = (float)hx[3];
    } else {
      xv = __builtin_nontemporal_load((const f32x4*)(x32 + base));
      half4_t hx;
      hx[0] = (_Float16)xv[0]; hx[1] = (_Float16)xv[1];
      hx[2] = (_Float16)xv[2]; hx[3] = (_Float16)xv[3];
      *(half4_t*)(x16w + base) = hx;
    }
    float d = xv[0] * qv[0] + xv[1] * qv[1] + xv[2] * qv[2] + xv[3] * qv[3];
#pragma unroll
    for (int off = 32; off; off >>= 1) d += __shfl_xor(d, off);
    if (d > m) {  // wave-uniform after full-wave reduction
      float sc = __expf(m - d);
      ssum *= sc; racc *= sc;
      m = d;
    }
    float p = __expf(d - m);
    ssum += p;
    racc += p * xv;
  }

  if (lane == 0) { mw[w] = m; sw[w] = ssum; }
  *(f32x4*)(rw + w * FF + 4 * lane) = racc;
  __syncthreads();
  float M = fmaxf(fmaxf(mw[0], mw[1]), fmaxf(mw[2], mw[3]));
  float e0 = (mw[0] == -INFINITY) ? 0.f : __expf(mw[0] - M);
  float e1 = (mw[1] == -INFINITY) ? 0.f : __expf(mw[1] - M);
  float e2 = (mw[2] == -INFINITY) ? 0.f : __expf(mw[2] - M);
  float e3 = (mw[3] == -INFINITY) ? 0.f : __expf(mw[3] - M);
  float denom = sw[0] * e0 + sw[1] * e1 + sw[2] * e2 + sw[3] * e3;
  float rs = rw[tid] * e0 + rw[FF + tid] * e1 + rw[2 * FF + tid] * e2 +
             rw[3 * FF + tid] * e3;
  float r = rs / (denom + 1e-16f);
  if (cnt == 0) r = 0.f;
  qstar[(size_t)g * 512 + FF + tid] = r;
  q16out[(size_t)g * 512 + FF + tid] = (_Float16)r;
  __syncthreads();  // LDS reused by next graph
}

// ---- gates GEMM + LSTM pointwise for one 64g x 32f tile (R3-proven) ----
__device__ __forceinline__ void gemm_phase(
    int bid, const _Float16* __restrict__ q16in, const _Float16* __restrict__ w16,
    const float* __restrict__ bias, float* __restrict__ c,
    float* __restrict__ qstar, _Float16* __restrict__ q16out) {
  int lane = threadIdx.x & 63, w = threadIdx.x >> 6;
  int wm = w >> 1, wn = w & 1;
  int bx = bid & 63, by = bid >> 6;        // 64 g-tiles x 8 f-tiles
  int g0 = bx * 64 + wm * 32;
  int f0 = by * 32 + wn * 16;
  int lr = lane & 15, kq = lane >> 4;

  f32x4 acc[2][4];
#pragma unroll
  for (int m = 0; m < 2; ++m)
#pragma unroll
    for (int gt = 0; gt < 4; ++gt) acc[m][gt] = (f32x4){0.f, 0.f, 0.f, 0.f};

  for (int k0 = 0; k0 < 512; k0 += 32) {
    int kk = k0 + kq * 8;
    half8_t a[2], b[4];
#pragma unroll
    for (int m = 0; m < 2; ++m)
      a[m] = *(const half8_t*)(q16in + (size_t)(g0 + m * 16 + lr) * 512 + kk);
#pragma unroll
    for (int gt = 0; gt < 4; ++gt)
      b[gt] = *(const half8_t*)(w16 + (size_t)(gt * 256 + f0 + lr) * 512 + kk);
#pragma unroll
    for (int m = 0; m < 2; ++m)
#pragma unroll
      for (int gt = 0; gt < 4; ++gt)
        acc[m][gt] = __builtin_amdgcn_mfma_f32_16x16x32_f16(a[m], b[gt], acc[m][gt], 0, 0, 0);
  }

  int f = f0 + lr;
#pragma unroll
  for (int m = 0; m < 2; ++m)
#pragma unroll
    for (int r = 0; r < 4; ++r) {
      int g = g0 + m * 16 + kq * 4 + r;
      float ig = acc[m][0][r] + bias[f];
      float fg = acc[m][1][r] + bias[f + 256];
      float gv = acc[m][2][r] + bias[f + 512];
      float og = acc[m][3][r] + bias[f + 768];
      float si = 1.f / (1.f + __expf(-ig));
      float sf = 1.f / (1.f + __expf(-fg));
      float so = 1.f / (1.f + __expf(-og));
      size_t ci = (size_t)g * FF + f;
      float cv = sf * c[ci] + si * tanhf(gv);
      float hv = so * tanhf(cv);
      c[ci] = cv;
      qstar[(size_t)g * 512 + f] = hv;
      q16out[(size_t)g * 512 + f] = (_Float16)hv;
    }
}

// ---- the whole Set2Set in one persistent kernel ----
__global__ __launch_bounds__(256, 2) void set2set_kernel(
    const float* __restrict__ x32, const int* __restrict__ batch,
    const float* __restrict__ Wih, const float* __restrict__ Whh,
    const float* __restrict__ bih, const float* __restrict__ bhh,
    float* __restrict__ qstar, float* __restrict__ c,
    _Float16* __restrict__ q16a, _Float16* __restrict__ q16b,
    _Float16* __restrict__ w16, float* __restrict__ bias,
    _Float16* __restrict__ x16, int* __restrict__ bar) {
  int bid = blockIdx.x;
  int tid = threadIdx.x;

  __shared__ int sg[9];                       // starts[b*8 .. b*8+8]
  __shared__ __align__(16) float h_sh[FF];    // t0 q-row (graph-independent)
  __shared__ __align__(16) float rw[4 * FF];
  __shared__ float mw[4], sw[4];

  // ---- prep (no barrier needed before t0 attn) ----
#pragma unroll
  for (int e = 0; e < 4; ++e) {               // w16 rows 2*bid .. 2*bid+1
    int idx = bid * 1024 + e * 256 + tid;
    int j = idx >> 9, k = idx & 511;
    float v = Wih[(size_t)j * 512 + k];
    if (k < 256) v += Whh[(size_t)j * 256 + k];
    w16[idx] = (_Float16)v;
  }
  if (bid == 0)                               // bias array for gemm phases
    for (int e = tid; e < 1024; e += 256) bias[e] = bih[e] + bhh[e];
  if (tid < 9) {                              // local segment starts
    int gv = bid * 8 + tid;
    if (gv >= GG) sg[tid] = NN;
    else {
      int lo = 0, hi = NN;
      while (lo < hi) {
        int mid = (lo + hi) >> 1;
        if (batch[mid] < gv) lo = mid + 1; else hi = mid;
      }
      sg[tid] = lo;
    }
  }

  // t0 LSTM: gates = bias only (q_star = h = c = 0) -> h identical for all g
  float bi = bih[tid] + bhh[tid];
  float bg = bih[tid + 512] + bhh[tid + 512];
  float bo = bih[tid + 768] + bhh[tid + 768];
  float si0 = 1.f / (1.f + __expf(-bi));
  float so0 = 1.f / (1.f + __expf(-bo));
  float cv0 = si0 * tanhf(bg);
  float hv0 = so0 * tanhf(cv0);
  h_sh[tid] = hv0;
  __syncthreads();

  // ---- t = 0: attn for 8 graphs, x32 NT read + x16 mirror write ----
  for (int i = 0; i < 8; ++i) {
    int g = bid * 8 + i;
    c[(size_t)g * FF + tid] = cv0;
    qstar[(size_t)g * 512 + tid] = hv0;
    q16a[(size_t)g * 512 + tid] = (_Float16)hv0;
    attn_graph<1>(g, sg[i], sg[i + 1] - sg[i], x32, nullptr, x16,
                  h_sh, qstar, q16a, rw, mw, sw);
  }

  int ep = 0;
  grid_barrier(bar, ++ep, bid);

  // ---- t = 1..5 ----
  for (int t = 1; t < TT; ++t) {
    _Float16* qin  = (t & 1) ? q16a : q16b;
    _Float16* qout = (t & 1) ? q16b : q16a;
    gemm_phase(bid, qin, w16, bias, c, qstar, qout);
    grid_barrier(bar, ++ep, bid);
    for (int i = 0; i < 8; ++i) {
      int g = bid * 8 + i;
      attn_graph<2>(g, sg[i], sg[i + 1] - sg[i], nullptr, x16, nullptr,
                    qstar + (size_t)g * 512, qstar, qout, rw, mw, sw);
    }
    if (t < TT - 1) grid_barrier(bar, ++ep, bid);
  }
}

// ---------------- launcher ----------------
extern "C" void kernel_launch(void* const* d_in, const int* in_sizes, int n_in,
                              void* d_out, int out_size, void* d_ws, size_t ws_size,
                              hipStream_t stream) {
  const float* x   = (const float*)d_in[0];
  const int* batch = (const int*)d_in[1];
  // d_in[2] = size (4096), hard-coded
  const float* Wih = (const float*)d_in[3];
  const float* Whh = (const float*)d_in[4];
  const float* bih = (const float*)d_in[5];
  const float* bhh = (const float*)d_in[6];
  float* qstar = (float*)d_out;  // [GG, 512]; final value IS the output

  uint8_t* p = (uint8_t*)d_ws;
  auto alloc = [&](size_t bytes) {
    uint8_t* q = p;
    p += (bytes + 255) & ~(size_t)255;
    return q;
  };
  float* c_st    = (float*)alloc((size_t)GG * FF * 4);            // 4 MB
  _Float16* q16a = (_Float16*)alloc((size_t)GG * 2 * FF * 2);     // 4 MB
  _Float16* q16b = (_Float16*)alloc((size_t)GG * 2 * FF * 2);     // 4 MB
  _Float16* w16  = (_Float16*)alloc((size_t)4 * FF * 2 * FF * 2); // 1 MB
  float* bias    = (float*)alloc((size_t)4 * FF * 4);
  _Float16* x16  = (_Float16*)alloc((size_t)NN * FF * 2);         // 128 MB
  int* bar       = (int*)alloc(1024 * 4);                         // barrier state

  hipMemsetAsync(bar, 0, 1024 * 4, stream);  // epochs/counters start at 0
  set2set_kernel<<<NBLK, 256, 0, stream>>>(
      x, batch, Wih, Whh, bih, bhh, qstar, c_st, q16a, q16b, w16, bias, x16, bar);
}

// Round 6
// 332.261 us; speedup vs baseline: 5.6176x; 5.6176x over previous
//
#include <hip/hip_runtime.h>
#include <cstdint>
#include <cstddef>

#define NN 250000   // nodes
#define FF 256      // channels
#define GG 4096     // graphs
#define TT 6        // processing steps

typedef _Float16 half8_t __attribute__((ext_vector_type(8)));
typedef _Float16 half4_t __attribute__((ext_vector_type(4)));
typedef _Float16 half2_t __attribute__((ext_vector_type(2)));
typedef float f32x4 __attribute__((ext_vector_type(4)));

__device__ __forceinline__ float fdot2f(half2_t a, half2_t b, float c) {
#if __has_builtin(__builtin_amdgcn_fdot2)
  return __builtin_amdgcn_fdot2(a, b, c, false);
#else
  return c + (float)a[0] * (float)b[0] + (float)a[1] * (float)b[1];
#endif
}

// ---------------- one-time prep (merged: w16 + bias + starts) ----------------
__global__ __launch_bounds__(256) void prep_kernel(
    const float* __restrict__ Wih, const float* __restrict__ Whh,
    const float* __restrict__ bih, const float* __restrict__ bhh,
    const int* __restrict__ batch, _Float16* __restrict__ w16,
    float* __restrict__ bias, int* __restrict__ starts) {
  int idx = blockIdx.x * 256 + threadIdx.x;
  if (idx < 4 * FF) bias[idx] = bih[idx] + bhh[idx];
  if (idx <= GG) {
    int lo = 0, hi = NN;
    if (idx == GG) lo = NN;
    else while (lo < hi) {
      int mid = (lo + hi) >> 1;
      if (batch[mid] < idx) lo = mid + 1; else hi = mid;
    }
    starts[idx] = lo;
  }
  if (idx < 4 * FF * 2 * FF) {
    int j = idx >> 9, k = idx & 511;
    float v = Wih[(size_t)j * 512 + k];
    if (k < FF) v += Whh[(size_t)j * FF + k];
    w16[idx] = (_Float16)v;
  }
}

// ---------------- fused gates-GEMM + LSTM pointwise (R3-proven) ----------------
// Block: 64 graphs x 32 f; W-cols {f, f+256, f+512, f+768}. Grid (64, 8).
__global__ __launch_bounds__(256) void gemm_lstm_kernel(
    const _Float16* __restrict__ q16in, const _Float16* __restrict__ w16,
    const float* __restrict__ bias, float* __restrict__ c,
    float* __restrict__ qstar, _Float16* __restrict__ q16out) {
  int lane = threadIdx.x & 63;
  int w    = threadIdx.x >> 6;
  int wm = w >> 1, wn = w & 1;
  int g0 = blockIdx.x * 64 + wm * 32;
  int f0 = blockIdx.y * 32 + wn * 16;
  int lr = lane & 15, kq = lane >> 4;

  f32x4 acc[2][4];
#pragma unroll
  for (int m = 0; m < 2; ++m)
#pragma unroll
    for (int gt = 0; gt < 4; ++gt) acc[m][gt] = (f32x4){0.f, 0.f, 0.f, 0.f};

  for (int k0 = 0; k0 < 512; k0 += 32) {
    int kk = k0 + kq * 8;
    half8_t a[2], b[4];
#pragma unroll
    for (int m = 0; m < 2; ++m)
      a[m] = *(const half8_t*)(q16in + (size_t)(g0 + wm * 0 + m * 16 + lr) * 512 + kk);
#pragma unroll
    for (int gt = 0; gt < 4; ++gt)
      b[gt] = *(const half8_t*)(w16 + (size_t)(gt * 256 + f0 + lr) * 512 + kk);
#pragma unroll
    for (int m = 0; m < 2; ++m)
#pragma unroll
      for (int gt = 0; gt < 4; ++gt)
        acc[m][gt] = __builtin_amdgcn_mfma_f32_16x16x32_f16(a[m], b[gt], acc[m][gt], 0, 0, 0);
  }

  int f = f0 + lr;
#pragma unroll
  for (int m = 0; m < 2; ++m)
#pragma unroll
    for (int r = 0; r < 4; ++r) {
      int g = g0 + m * 16 + kq * 4 + r;
      float ig = acc[m][0][r] + bias[f];
      float fg = acc[m][1][r] + bias[f + 256];
      float gv = acc[m][2][r] + bias[f + 512];
      float og = acc[m][3][r] + bias[f + 768];
      float si = 1.f / (1.f + __expf(-ig));
      float sf = 1.f / (1.f + __expf(-fg));
      float so = 1.f / (1.f + __expf(-og));
      size_t ci = (size_t)g * FF + f;
      float cv = sf * c[ci] + si * tanhf(gv);
      float hv = so * tanhf(cv);
      c[ci] = cv;
      qstar[(size_t)g * 512 + f] = hv;
      q16out[(size_t)g * 512 + f] = (_Float16)hv;
    }
}

// ---------------- t=0 attention: f32 sweep + x16 mirror write ----------------
// One block (4 waves)/graph, 1 node/wave/iter (16 B/lane), unroll-2 for MLP.
__global__ __launch_bounds__(256) void attn0_kernel(
    const float* __restrict__ x32, _Float16* __restrict__ x16w,
    const int* __restrict__ starts, const float* __restrict__ bih,
    const float* __restrict__ bhh, float* __restrict__ c,
    float* __restrict__ qstar, _Float16* __restrict__ q16out) {
  int g = blockIdx.x, tid = threadIdx.x, lane = tid & 63, w = tid >> 6;
  __shared__ __align__(16) float h_sh[FF];
  __shared__ __align__(16) float rw[4][FF];
  __shared__ float mw[4], sw[4];

  // t0 LSTM: gates = bias only (q_star = h = c = 0); h0 same for all graphs
  float bi = bih[tid] + bhh[tid];
  float bg = bih[tid + 512] + bhh[tid + 512];
  float bo = bih[tid + 768] + bhh[tid + 768];
  float si0 = 1.f / (1.f + __expf(-bi));
  float so0 = 1.f / (1.f + __expf(-bo));
  float cv0 = si0 * tanhf(bg);
  float hv0 = so0 * tanhf(cv0);
  c[(size_t)g * FF + tid] = cv0;
  qstar[(size_t)g * 512 + tid] = hv0;
  q16out[(size_t)g * 512 + tid] = (_Float16)hv0;
  h_sh[tid] = hv0;
  __syncthreads();

  f32x4 qv = *(const f32x4*)&h_sh[4 * lane];
  int s0 = starts[g];
  int cnt = starts[g + 1] - s0;

  float m = -INFINITY, ssum = 0.f;
  f32x4 racc = {0.f, 0.f, 0.f, 0.f};
#pragma unroll 2
  for (int i = w; i < cnt; i += 4) {
    size_t base = (size_t)(s0 + i) * FF + 4 * lane;
    f32x4 xv = __builtin_nontemporal_load((const f32x4*)(x32 + base));
    half4_t hx;
    hx[0] = (_Float16)xv[0]; hx[1] = (_Float16)xv[1];
    hx[2] = (_Float16)xv[2]; hx[3] = (_Float16)xv[3];
    *(half4_t*)(x16w + base) = hx;
    float d = xv[0] * qv[0] + xv[1] * qv[1] + xv[2] * qv[2] + xv[3] * qv[3];
#pragma unroll
    for (int off = 32; off; off >>= 1) d += __shfl_xor(d, off);
    if (d > m) {  // wave-uniform
      float sc = __expf(m - d);
      ssum *= sc; racc *= sc;
      m = d;
    }
    float p = __expf(d - m);
    ssum += p;
    racc += p * xv;
  }

  if (lane == 0) { mw[w] = m; sw[w] = ssum; }
  *(f32x4*)&rw[w][4 * lane] = racc;
  __syncthreads();
  float M = fmaxf(fmaxf(mw[0], mw[1]), fmaxf(mw[2], mw[3]));
  float e0 = (mw[0] == -INFINITY) ? 0.f : __expf(mw[0] - M);
  float e1 = (mw[1] == -INFINITY) ? 0.f : __expf(mw[1] - M);
  float e2 = (mw[2] == -INFINITY) ? 0.f : __expf(mw[2] - M);
  float e3 = (mw[3] == -INFINITY) ? 0.f : __expf(mw[3] - M);
  float denom = sw[0] * e0 + sw[1] * e1 + sw[2] * e2 + sw[3] * e3;
  float rs = rw[0][tid] * e0 + rw[1][tid] * e1 + rw[2][tid] * e2 + rw[3][tid] * e3;
  float r = rs / (denom + 1e-16f);
  if (cnt == 0) r = 0.f;
  qstar[(size_t)g * 512 + FF + tid] = r;
  q16out[(size_t)g * 512 + FF + tid] = (_Float16)r;
}

// ---------------- t>=1 attention: f16, 2 nodes/wave, fdot2, unroll-4 ----------------
// Lanes 0-31 own node i (8 ch/lane, one 16 B load), lanes 32-63 own node i+1.
// 5-level shfl within halves + 1 cross-half exchange; rescale wave-uniform.
__global__ __launch_bounds__(256) void attn_kernel(
    const _Float16* __restrict__ x16, const int* __restrict__ starts,
    float* __restrict__ qstar, _Float16* __restrict__ q16) {
  int g = blockIdx.x, tid = threadIdx.x, lane = tid & 63, w = tid >> 6;
  int sl = lane & 31, hf = lane >> 5;
  __shared__ __align__(16) float rw[4][FF];
  __shared__ float mw[4], sw[4];

  // q (= h half of q_star, just written by gemm) in f16: chs sl*8..+8
  half8_t qh = *(const half8_t*)(q16 + (size_t)g * 512 + sl * 8);

  int s0 = starts[g];
  int cnt = starts[g + 1] - s0;

  float m = -INFINITY, ssum = 0.f;
  float racc[8];
#pragma unroll
  for (int j = 0; j < 8; ++j) racc[j] = 0.f;

#pragma unroll 4
  for (int i0 = w * 2; i0 < cnt; i0 += 8) {
    int idx = i0 + hf;
    bool valid = idx < cnt;
    int node = valid ? idx : cnt - 1;
    half8_t hx = *(const half8_t*)(x16 + (size_t)(s0 + node) * FF + sl * 8);
    float d = fdot2f((half2_t){hx[0], hx[1]}, (half2_t){qh[0], qh[1]}, 0.f);
    d = fdot2f((half2_t){hx[2], hx[3]}, (half2_t){qh[2], qh[3]}, d);
    d = fdot2f((half2_t){hx[4], hx[5]}, (half2_t){qh[4], qh[5]}, d);
    d = fdot2f((half2_t){hx[6], hx[7]}, (half2_t){qh[6], qh[7]}, d);
#pragma unroll
    for (int off = 1; off <= 16; off <<= 1) d += __shfl_xor(d, off);
    if (!valid) d = -INFINITY;          // uniform per 32-lane half
    float dother = __shfl_xor(d, 32);
    float gm = fmaxf(d, dother);        // identical across the wave
    if (gm > m) {
      float sc = __expf(m - gm);        // first hit: exp(-inf)=0
      ssum *= sc;
#pragma unroll
      for (int j = 0; j < 8; ++j) racc[j] *= sc;
      m = gm;
    }
    float p = __expf(d - m);            // invalid half: exp(-inf)=0
    ssum += p;
#pragma unroll
    for (int j = 0; j < 8; ++j) racc[j] += p * (float)hx[j];
  }

  // combine the two halves of the wave
  ssum += __shfl_xor(ssum, 32);
#pragma unroll
  for (int j = 0; j < 8; ++j) racc[j] += __shfl_xor(racc[j], 32);

  if (lane == 0) { mw[w] = m; sw[w] = ssum; }
  if (hf == 0) {
    f32x4 lo = {racc[0], racc[1], racc[2], racc[3]};
    f32x4 hi = {racc[4], racc[5], racc[6], racc[7]};
    *(f32x4*)&rw[w][sl * 8] = lo;
    *(f32x4*)&rw[w][sl * 8 + 4] = hi;
  }
  __syncthreads();

  float M = fmaxf(fmaxf(mw[0], mw[1]), fmaxf(mw[2], mw[3]));
  float e0 = (mw[0] == -INFINITY) ? 0.f : __expf(mw[0] - M);
  float e1 = (mw[1] == -INFINITY) ? 0.f : __expf(mw[1] - M);
  float e2 = (mw[2] == -INFINITY) ? 0.f : __expf(mw[2] - M);
  float e3 = (mw[3] == -INFINITY) ? 0.f : __expf(mw[3] - M);
  float denom = sw[0] * e0 + sw[1] * e1 + sw[2] * e2 + sw[3] * e3;
  float rs = rw[0][tid] * e0 + rw[1][tid] * e1 + rw[2][tid] * e2 + rw[3][tid] * e3;
  float r = rs / (denom + 1e-16f);
  if (cnt == 0) r = 0.f;
  qstar[(size_t)g * 512 + FF + tid] = r;
  q16[(size_t)g * 512 + FF + tid] = (_Float16)r;
}

// ---------------- launcher ----------------
extern "C" void kernel_launch(void* const* d_in, const int* in_sizes, int n_in,
                              void* d_out, int out_size, void* d_ws, size_t ws_size,
                              hipStream_t stream) {
  const float* x   = (const float*)d_in[0];
  const int* batch = (const int*)d_in[1];
  // d_in[2] = size (4096), hard-coded
  const float* Wih = (const float*)d_in[3];
  const float* Whh = (const float*)d_in[4];
  const float* bih = (const float*)d_in[5];
  const float* bhh = (const float*)d_in[6];
  float* qstar = (float*)d_out;  // [GG, 512]; final value IS the output

  uint8_t* p = (uint8_t*)d_ws;
  auto alloc = [&](size_t bytes) {
    uint8_t* q = p;
    p += (bytes + 255) & ~(size_t)255;
    return q;
  };
  float* c_st    = (float*)alloc((size_t)GG * FF * 4);            // 4 MB
  _Float16* q16a = (_Float16*)alloc((size_t)GG * 2 * FF * 2);     // 4 MB
  _Float16* q16b = (_Float16*)alloc((size_t)GG * 2 * FF * 2);     // 4 MB
  _Float16* w16  = (_Float16*)alloc((size_t)4 * FF * 2 * FF * 2); // 1 MB
  float* bias    = (float*)alloc((size_t)4 * FF * 4);
  int* starts    = (int*)alloc((size_t)(GG + 1) * 4);
  _Float16* x16  = (_Float16*)alloc((size_t)NN * FF * 2);         // 128 MB

  prep_kernel<<<(4 * FF * 2 * FF) / 256, 256, 0, stream>>>(
      Wih, Whh, bih, bhh, batch, w16, bias, starts);

  // t = 0: bias-only LSTM + f32 sweep + x16 mirror
  attn0_kernel<<<GG, 256, 0, stream>>>(
      x, x16, starts, bih, bhh, c_st, qstar, q16a);

  for (int t = 1; t < TT; ++t) {
    _Float16* qin  = (t & 1) ? q16a : q16b;
    _Float16* qout = (t & 1) ? q16b : q16a;
    gemm_lstm_kernel<<<dim3(64, 8), 256, 0, stream>>>(
        qin, w16, bias, c_st, qstar, qout);
    attn_kernel<<<GG, 256, 0, stream>>>(x16, starts, qstar, qout);
  }
}

// Round 8
// 329.249 us; speedup vs baseline: 5.6690x; 1.0091x over previous
//
#include <hip/hip_runtime.h>
#include <cstdint>
#include <cstddef>

#define NN 250000   // nodes
#define FF 256      // channels
#define GG 4096     // graphs
#define TT 6        // processing steps

typedef _Float16 half8_t __attribute__((ext_vector_type(8)));
typedef _Float16 half4_t __attribute__((ext_vector_type(4)));
typedef _Float16 half2_t __attribute__((ext_vector_type(2)));
typedef float f32x4 __attribute__((ext_vector_type(4)));

__device__ __forceinline__ float fdot2f(half2_t a, half2_t b, float c) {
#if __has_builtin(__builtin_amdgcn_fdot2)
  return __builtin_amdgcn_fdot2(a, b, c, false);
#else
  return c + (float)a[0] * (float)b[0] + (float)a[1] * (float)b[1];
#endif
}

__device__ __forceinline__ float dot8(half8_t x, half8_t q) {
  float d = fdot2f((half2_t){x[0], x[1]}, (half2_t){q[0], q[1]}, 0.f);
  d = fdot2f((half2_t){x[2], x[3]}, (half2_t){q[2], q[3]}, d);
  d = fdot2f((half2_t){x[4], x[5]}, (half2_t){q[4], q[5]}, d);
  d = fdot2f((half2_t){x[6], x[7]}, (half2_t){q[6], q[7]}, d);
  return d;
}

// ---------------- t=0: fused prep + bias-LSTM + f32 sweep + x16 mirror ----------------
// Block g: computes its own starts (2 binary searches) and publishes starts[g];
// blocks < 512 also build 1024 elements of w16 each (512*1024 = 524288 = |w16|).
__global__ __launch_bounds__(256) void attn0_kernel(
    const float* __restrict__ x32, const int* __restrict__ batch,
    const float* __restrict__ Wih, const float* __restrict__ Whh,
    const float* __restrict__ bih, const float* __restrict__ bhh,
    _Float16* __restrict__ w16, int* __restrict__ starts,
    float* __restrict__ c, _Float16* __restrict__ x16w,
    _Float16* __restrict__ q16out) {
  int g = blockIdx.x, tid = threadIdx.x, lane = tid & 63, w = tid >> 6;
  __shared__ int sgs[2];
  __shared__ __align__(16) float h_sh[FF];
  __shared__ __align__(16) float rw[4][FF];
  __shared__ float mw[4], sw[4];

  // segment starts: tid0 -> starts[g], tid1 -> starts[g+1] (redundant across
  // blocks but identical; block GG-1's tid1 covers starts[GG]=NN)
  if (tid < 2) {
    int target = g + tid;
    int lo = 0;
    if (target >= GG) lo = NN;
    else {
      int hi = NN;
      while (lo < hi) {
        int mid = (lo + hi) >> 1;
        if (batch[mid] < target) lo = mid + 1; else hi = mid;
      }
    }
    sgs[tid] = lo;
    starts[g + tid] = lo;
  }

  // w16 prep: blocks 0..511, 4 elements/thread -> exactly 524288 elements.
  // (R7 BUG was g<1024 here: 2x overrun into `starts` -> device abort.)
  if (g < 512) {
#pragma unroll
    for (int e = 0; e < 4; ++e) {
      int idx = g * 1024 + e * 256 + tid;   // < 524288; j = idx>>9 < 1024 ok
      int j = idx >> 9, k = idx & 511;
      float v = Wih[(size_t)j * 512 + k];
      if (k < FF) v += Whh[(size_t)j * FF + k];
      w16[idx] = (_Float16)v;
    }
  }

  // t0 LSTM: gates = bias only (q_star = h = c = 0); identical for all graphs
  float bi = bih[tid] + bhh[tid];
  float bg = bih[tid + 512] + bhh[tid + 512];
  float bo = bih[tid + 768] + bhh[tid + 768];
  float si0 = 1.f / (1.f + __expf(-bi));
  float so0 = 1.f / (1.f + __expf(-bo));
  float cv0 = si0 * tanhf(bg);
  float hv0 = so0 * tanhf(cv0);
  c[(size_t)g * FF + tid] = cv0;
  q16out[(size_t)g * 512 + tid] = (_Float16)hv0;  // h half for t1 gemm
  h_sh[tid] = hv0;
  __syncthreads();

  f32x4 qv = *(const f32x4*)&h_sh[4 * lane];
  int s0 = sgs[0], cnt = sgs[1] - sgs[0];

  float m = -INFINITY, ssum = 0.f;
  f32x4 racc = {0.f, 0.f, 0.f, 0.f};
#pragma unroll 4
  for (int i = w; i < cnt; i += 4) {
    size_t base = (size_t)(s0 + i) * FF + 4 * lane;
    f32x4 xv = __builtin_nontemporal_load((const f32x4*)(x32 + base));
    half4_t hx;
    hx[0] = (_Float16)xv[0]; hx[1] = (_Float16)xv[1];
    hx[2] = (_Float16)xv[2]; hx[3] = (_Float16)xv[3];
    *(half4_t*)(x16w + base) = hx;
    float d = xv[0] * qv[0] + xv[1] * qv[1] + xv[2] * qv[2] + xv[3] * qv[3];
#pragma unroll
    for (int off = 32; off; off >>= 1) d += __shfl_xor(d, off);
    if (d > m) {  // wave-uniform
      float sc = __expf(m - d);
      ssum *= sc; racc *= sc;
      m = d;
    }
    float p = __expf(d - m);
    ssum += p;
    racc += p * xv;
  }

  if (lane == 0) { mw[w] = m; sw[w] = ssum; }
  *(f32x4*)&rw[w][4 * lane] = racc;
  __syncthreads();
  float M = fmaxf(fmaxf(mw[0], mw[1]), fmaxf(mw[2], mw[3]));
  float e0 = (mw[0] == -INFINITY) ? 0.f : __expf(mw[0] - M);
  float e1 = (mw[1] == -INFINITY) ? 0.f : __expf(mw[1] - M);
  float e2 = (mw[2] == -INFINITY) ? 0.f : __expf(mw[2] - M);
  float e3 = (mw[3] == -INFINITY) ? 0.f : __expf(mw[3] - M);
  float denom = sw[0] * e0 + sw[1] * e1 + sw[2] * e2 + sw[3] * e3;
  float rs = rw[0][tid] * e0 + rw[1][tid] * e1 + rw[2][tid] * e2 + rw[3][tid] * e3;
  float r = rs / (denom + 1e-16f);
  if (cnt == 0) r = 0.f;
  q16out[(size_t)g * 512 + FF + tid] = (_Float16)r;  // r half for t1 gemm
}

// ---------------- fused gates-GEMM + LSTM pointwise ----------------
// Block: 64 graphs x 32 f; W-cols {f, f+256, f+512, f+768}. Grid (64, 8).
// Grid-limited to 2 blocks/CU, so unroll-4's extra VGPRs are free; 4x the
// L2 loads in flight. qstar h-write only on the last step (else dead).
template <bool LAST>
__global__ __launch_bounds__(256) void gemm_lstm_kernel(
    const _Float16* __restrict__ q16in, const _Float16* __restrict__ w16,
    const float* __restrict__ bih, const float* __restrict__ bhh,
    float* __restrict__ c, float* __restrict__ qstar,
    _Float16* __restrict__ q16out) {
  int lane = threadIdx.x & 63;
  int w    = threadIdx.x >> 6;
  int wm = w >> 1, wn = w & 1;
  int g0 = blockIdx.x * 64 + wm * 32;
  int f0 = blockIdx.y * 32 + wn * 16;
  int lr = lane & 15, kq = lane >> 4;

  f32x4 acc[2][4];
#pragma unroll
  for (int m = 0; m < 2; ++m)
#pragma unroll
    for (int gt = 0; gt < 4; ++gt) acc[m][gt] = (f32x4){0.f, 0.f, 0.f, 0.f};

#pragma unroll 4
  for (int k0 = 0; k0 < 512; k0 += 32) {
    int kk = k0 + kq * 8;
    half8_t a[2], b[4];
#pragma unroll
    for (int m = 0; m < 2; ++m)
      a[m] = *(const half8_t*)(q16in + (size_t)(g0 + m * 16 + lr) * 512 + kk);
#pragma unroll
    for (int gt = 0; gt < 4; ++gt)
      b[gt] = *(const half8_t*)(w16 + (size_t)(gt * 256 + f0 + lr) * 512 + kk);
#pragma unroll
    for (int m = 0; m < 2; ++m)
#pragma unroll
      for (int gt = 0; gt < 4; ++gt)
        acc[m][gt] = __builtin_amdgcn_mfma_f32_16x16x32_f16(a[m], b[gt], acc[m][gt], 0, 0, 0);
  }

  int f = f0 + lr;
  float bi  = bih[f]       + bhh[f];
  float bf2 = bih[f + 256] + bhh[f + 256];
  float bg  = bih[f + 512] + bhh[f + 512];
  float bo  = bih[f + 768] + bhh[f + 768];
#pragma unroll
  for (int m = 0; m < 2; ++m)
#pragma unroll
    for (int r = 0; r < 4; ++r) {
      int g = g0 + m * 16 + kq * 4 + r;
      float ig = acc[m][0][r] + bi;
      float fg = acc[m][1][r] + bf2;
      float gv = acc[m][2][r] + bg;
      float og = acc[m][3][r] + bo;
      float si = 1.f / (1.f + __expf(-ig));
      float sf = 1.f / (1.f + __expf(-fg));
      float so = 1.f / (1.f + __expf(-og));
      size_t ci = (size_t)g * FF + f;
      float cv = sf * c[ci] + si * tanhf(gv);
      float hv = so * tanhf(cv);
      c[ci] = cv;
      if (LAST) qstar[(size_t)g * 512 + f] = hv;
      q16out[(size_t)g * 512 + f] = (_Float16)hv;
    }
}

// ---------------- t>=1 attention: f16, 2 nodes/wave, manual 4-group MLP ----------------
// Per loop iteration a wave loads 4 half8 tiles (8 nodes across its two
// 32-lane halves) BEFORE any reduction: 4 loads in flight, 4 interleaved
// shuffle trees, one rescale check per 8 nodes.
template <bool LAST>
__global__ __launch_bounds__(256) void attn_kernel(
    const _Float16* __restrict__ x16, const int* __restrict__ starts,
    float* __restrict__ qstar, _Float16* __restrict__ q16) {
  int g = blockIdx.x, tid = threadIdx.x, lane = tid & 63, w = tid >> 6;
  int sl = lane & 31, hf = lane >> 5;
  __shared__ __align__(16) float rw[4][FF];
  __shared__ float mw[4], sw[4];

  int s0 = starts[g];
  int cnt = starts[g + 1] - s0;
  half8_t qh = *(const half8_t*)(q16 + (size_t)g * 512 + sl * 8);

  float m = -INFINITY, ssum = 0.f;
  float racc[8];
#pragma unroll
  for (int e = 0; e < 8; ++e) racc[e] = 0.f;

  for (int i0 = w * 2; i0 < cnt; i0 += 32) {
    half8_t hx[4];
    float d[4];
    bool vld[4];
#pragma unroll
    for (int j = 0; j < 4; ++j) {
      int idx = i0 + j * 8 + hf;
      vld[j] = idx < cnt;
      int node = vld[j] ? idx : cnt - 1;
      hx[j] = *(const half8_t*)(x16 + (size_t)(s0 + node) * FF + sl * 8);
    }
#pragma unroll
    for (int j = 0; j < 4; ++j) d[j] = dot8(hx[j], qh);
#pragma unroll
    for (int off = 1; off <= 16; off <<= 1)
#pragma unroll
      for (int j = 0; j < 4; ++j) d[j] += __shfl_xor(d[j], off);
#pragma unroll
    for (int j = 0; j < 4; ++j) if (!vld[j]) d[j] = -INFINITY;
    float gm = -INFINITY;
#pragma unroll
    for (int j = 0; j < 4; ++j) {
      float dother = __shfl_xor(d[j], 32);
      gm = fmaxf(gm, fmaxf(d[j], dother));
    }
    if (gm > m) {  // wave-uniform; one rescale per 8 nodes
      float sc = __expf(m - gm);
      ssum *= sc;
#pragma unroll
      for (int e = 0; e < 8; ++e) racc[e] *= sc;
      m = gm;
    }
#pragma unroll
    for (int j = 0; j < 4; ++j) {
      float p = __expf(d[j] - m);  // invalid: exp(-inf)=0
      ssum += p;
#pragma unroll
      for (int e = 0; e < 8; ++e) racc[e] += p * (float)hx[j][e];
    }
  }

  // combine the two 32-lane halves of each wave
  ssum += __shfl_xor(ssum, 32);
#pragma unroll
  for (int e = 0; e < 8; ++e) racc[e] += __shfl_xor(racc[e], 32);

  if (lane == 0) { mw[w] = m; sw[w] = ssum; }
  if (hf == 0) {
    f32x4 lo = {racc[0], racc[1], racc[2], racc[3]};
    f32x4 hi = {racc[4], racc[5], racc[6], racc[7]};
    *(f32x4*)&rw[w][sl * 8] = lo;
    *(f32x4*)&rw[w][sl * 8 + 4] = hi;
  }
  __syncthreads();

  float M = fmaxf(fmaxf(mw[0], mw[1]), fmaxf(mw[2], mw[3]));
  float e0 = (mw[0] == -INFINITY) ? 0.f : __expf(mw[0] - M);
  float e1 = (mw[1] == -INFINITY) ? 0.f : __expf(mw[1] - M);
  float e2 = (mw[2] == -INFINITY) ? 0.f : __expf(mw[2] - M);
  float e3 = (mw[3] == -INFINITY) ? 0.f : __expf(mw[3] - M);
  float denom = sw[0] * e0 + sw[1] * e1 + sw[2] * e2 + sw[3] * e3;
  float rs = rw[0][tid] * e0 + rw[1][tid] * e1 + rw[2][tid] * e2 + rw[3][tid] * e3;
  float r = rs / (denom + 1e-16f);
  if (cnt == 0) r = 0.f;
  if (LAST) qstar[(size_t)g * 512 + FF + tid] = r;
  else      q16[(size_t)g * 512 + FF + tid] = (_Float16)r;
}

// ---------------- launcher ----------------
extern "C" void kernel_launch(void* const* d_in, const int* in_sizes, int n_in,
                              void* d_out, int out_size, void* d_ws, size_t ws_size,
                              hipStream_t stream) {
  const float* x   = (const float*)d_in[0];
  const int* batch = (const int*)d_in[1];
  // d_in[2] = size (4096), hard-coded
  const float* Wih = (const float*)d_in[3];
  const float* Whh = (const float*)d_in[4];
  const float* bih = (const float*)d_in[5];
  const float* bhh = (const float*)d_in[6];
  float* qstar = (float*)d_out;  // [GG, 512]; final step writes it

  uint8_t* p = (uint8_t*)d_ws;
  auto alloc = [&](size_t bytes) {
    uint8_t* q = p;
    p += (bytes + 255) & ~(size_t)255;
    return q;
  };
  float* c_st    = (float*)alloc((size_t)GG * FF * 4);            // 4 MB
  _Float16* q16a = (_Float16*)alloc((size_t)GG * 2 * FF * 2);     // 4 MB
  _Float16* q16b = (_Float16*)alloc((size_t)GG * 2 * FF * 2);     // 4 MB
  _Float16* w16  = (_Float16*)alloc((size_t)4 * FF * 2 * FF * 2); // 1 MB
  int* starts    = (int*)alloc((size_t)(GG + 1) * 4);
  _Float16* x16  = (_Float16*)alloc((size_t)NN * FF * 2);         // 128 MB

  // t = 0: prep (starts + w16) + bias-only LSTM + f32 sweep + x16 mirror
  attn0_kernel<<<GG, 256, 0, stream>>>(
      x, batch, Wih, Whh, bih, bhh, w16, starts, c_st, x16, q16a);

  for (int t = 1; t < TT; ++t) {
    _Float16* qin  = (t & 1) ? q16a : q16b;
    _Float16* qout = (t & 1) ? q16b : q16a;
    if (t < TT - 1) {
      gemm_lstm_kernel<false><<<dim3(64, 8), 256, 0, stream>>>(
          qin, w16, bih, bhh, c_st, qstar, qout);
      attn_kernel<false><<<GG, 256, 0, stream>>>(x16, starts, qstar, qout);
    } else {
      gemm_lstm_kernel<true><<<dim3(64, 8), 256, 0, stream>>>(
          qin, w16, bih, bhh, c_st, qstar, qout);
      attn_kernel<true><<<GG, 256, 0, stream>>>(x16, starts, qstar, qout);
    }
  }
}